// Round 3
// baseline (568.510 us; speedup 1.0000x reference)
//
#include <hip/hip_runtime.h>
#include <math.h>

#define T_LEN 1024
#define VV 512
#define BB 64
#define NB 16
#define ANG_STEP 0.006135923151542565f   // 2*pi/1024
#define FADE_S 487
#define FADE_E 537
#define ATL 64

__device__ constexpr int KB[NB] = {1,2,3,4,5,6,7,8,12,16,24,32,48,64,96,128};

// ---------------- Kernel 1: partial 16-bin DFT over a t-chunk ----------------
// grid (BB, TC), block 256. Thread owns v0=2*tid, v0+1.
// cos/sin from per-tile LDS table (broadcast reads on LDS pipe, frees VALU).
// Partials: xp[((b*TC + tc)*32 + q)*VV + v], q in [0,16)=re_j, [16,32)=im_j
template<int TLEN>
__global__ __launch_bounds__(256, 4) void k_dft_partial(const float* __restrict__ x,
                                                        float* __restrict__ xpart,
                                                        int tc_count) {
    const int b   = blockIdx.x;
    const int tc  = blockIdx.y;
    const int tid = threadIdx.x;
    const int t0  = tc * TLEN;

    __shared__ float2 tab[TLEN][NB];
    for (int i = tid; i < TLEN * NB; i += 256) {
        int t = i >> 4, j = i & 15;
        int idx = (KB[j] * (t0 + t)) & (T_LEN - 1);
        float ss, cc; sincosf(ANG_STEP * (float)idx, &ss, &cc);
        tab[t][j] = make_float2(cc, ss);
    }
    __syncthreads();

    float xr0[NB], xi0[NB], xr1[NB], xi1[NB];
#pragma unroll
    for (int j = 0; j < NB; ++j) { xr0[j] = xi0[j] = xr1[j] = xi1[j] = 0.0f; }

    const float2* xrd = (const float2*)(x + ((size_t)b * T_LEN + t0) * VV) + tid;

#define DFT_T(U, AV)                                    \
    do {                                                \
        _Pragma("unroll")                               \
        for (int j = 0; j < NB; ++j) {                  \
            float2 cs = tab[t + U][j];                  \
            xr0[j] = fmaf(AV.x, cs.x, xr0[j]);          \
            xi0[j] = fmaf(-AV.x, cs.y, xi0[j]);         \
            xr1[j] = fmaf(AV.y, cs.x, xr1[j]);          \
            xi1[j] = fmaf(-AV.y, cs.y, xi1[j]);         \
        }                                               \
    } while (0)

    for (int t = 0; t < TLEN; t += 4) {
        float2 a0 = xrd[(size_t)(t + 0) * (VV / 2)];
        float2 a1 = xrd[(size_t)(t + 1) * (VV / 2)];
        float2 a2 = xrd[(size_t)(t + 2) * (VV / 2)];
        float2 a3 = xrd[(size_t)(t + 3) * (VV / 2)];
        DFT_T(0, a0); DFT_T(1, a1); DFT_T(2, a2); DFT_T(3, a3);
    }
#undef DFT_T

    float2* o = (float2*)(xpart + (size_t)(b * tc_count + tc) * 32 * VV) + tid;
#pragma unroll
    for (int j = 0; j < NB; ++j) {
        o[(size_t)j        * (VV / 2)] = make_float2(xr0[j], xr1[j]);
        o[(size_t)(NB + j) * (VV / 2)] = make_float2(xi0[j], xi1[j]);
    }
}

// ---------------- Kernel 2: reduce partials, apply gains -> H ----------------
// grid (BB, NB): one j-bin per block for parallelism (1024 blocks).
// H layout: H[b][q][v], q: [0,16)=He_re, [16,32)=-He_im, [32,48)=Hl_re, [48,64)=-Hl_im
__global__ __launch_bounds__(256, 4) void k_combine(const float* __restrict__ xpart,
                                                    const float* __restrict__ ger,
                                                    const float* __restrict__ gei,
                                                    const float* __restrict__ glr,
                                                    const float* __restrict__ gli,
                                                    float* __restrict__ H, int tc_count) {
    const int b   = blockIdx.x;
    const int j   = blockIdx.y;
    const int tid = threadIdx.x;
    const int v0  = tid * 2;

    float re0 = 0.f, re1 = 0.f, im0 = 0.f, im1 = 0.f;
#pragma unroll 4
    for (int tc = 0; tc < tc_count; ++tc) {
        const float2* p = (const float2*)(xpart + (size_t)(b * tc_count + tc) * 32 * VV) + tid;
        float2 a  = p[(size_t)j        * (VV / 2)];
        float2 bb = p[(size_t)(NB + j) * (VV / 2)];
        re0 += a.x;  re1 += a.y;
        im0 += bb.x; im1 += bb.y;
    }

    const float scale = 2.0f / (float)T_LEN;
    float er0 = ger[v0 * NB + j],       ei0 = gei[v0 * NB + j];
    float lr0 = glr[v0 * NB + j],       li0 = gli[v0 * NB + j];
    float er1 = ger[(v0 + 1) * NB + j], ei1 = gei[(v0 + 1) * NB + j];
    float lr1 = glr[(v0 + 1) * NB + j], li1 = gli[(v0 + 1) * NB + j];

    float here0 = (re0 * er0 - im0 * ei0) * scale;
    float heim0 = (re0 * ei0 + im0 * er0) * scale;
    float hlre0 = (re0 * lr0 - im0 * li0) * scale;
    float hlim0 = (re0 * li0 + im0 * lr0) * scale;
    float here1 = (re1 * er1 - im1 * ei1) * scale;
    float heim1 = (re1 * ei1 + im1 * er1) * scale;
    float hlre1 = (re1 * lr1 - im1 * li1) * scale;
    float hlim1 = (re1 * li1 + im1 * lr1) * scale;

    float2* o = (float2*)(H + (size_t)b * 64 * VV) + tid;
    o[(size_t)j        * (VV / 2)] = make_float2(here0, here1);
    o[(size_t)(16 + j) * (VV / 2)] = make_float2(-heim0, -heim1);
    o[(size_t)(32 + j) * (VV / 2)] = make_float2(hlre0, hlre1);
    o[(size_t)(48 + j) * (VV / 2)] = make_float2(-hlim0, -hlim1);
}

// ---------------- Kernel 3a: pure-early/late tiles (single H set) ----------------
// grid (BB, 14): tiles 0..6 (early, He) and 9..15 (late, Hl). 64-reg H, high occupancy.
__global__ __launch_bounds__(256, 4) void k_apply_pure(const float* __restrict__ x,
                                                       const float* __restrict__ H,
                                                       float* __restrict__ out) {
    const int b    = blockIdx.x;
    const int ti   = blockIdx.y;
    const int tid  = threadIdx.x;
    const int tile = (ti < 7) ? ti : ti + 2;
    const int t0   = tile * ATL;
    const int qo   = (ti < 7) ? 0 : 32;

    __shared__ float2 tab[ATL][NB];
    for (int i = tid; i < ATL * NB; i += 256) {
        int t = i >> 4, j = i & 15;
        int idx = (KB[j] * (t0 + t)) & (T_LEN - 1);
        float ss, cc; sincosf(ANG_STEP * (float)idx, &ss, &cc);
        tab[t][j] = make_float2(cc, ss);
    }
    __syncthreads();

    float hr0[NB], hi0[NB], hr1[NB], hi1[NB];
    const float2* hp = (const float2*)(H + (size_t)b * 64 * VV) + tid;
#pragma unroll
    for (int j = 0; j < NB; ++j) {
        float2 a  = hp[(size_t)(qo + j)      * (VV / 2)]; hr0[j] = a.x;  hr1[j] = a.y;
        float2 bq = hp[(size_t)(qo + 16 + j) * (VV / 2)]; hi0[j] = bq.x; hi1[j] = bq.y;
    }

    const float2* xrd = (const float2*)(x + ((size_t)b * T_LEN + t0) * VV) + tid;
    float2*       ow  = (float2*)(out + ((size_t)b * T_LEN + t0) * VV) + tid;

#define APPLY_T(U, AV)                                   \
    do {                                                 \
        float s0 = 0.f, s1 = 0.f;                        \
        _Pragma("unroll")                                \
        for (int j = 0; j < NB; ++j) {                   \
            float2 cs = tab[t + U][j];                   \
            s0 = fmaf(hr0[j], cs.x, s0);                 \
            s0 = fmaf(hi0[j], cs.y, s0);                 \
            s1 = fmaf(hr1[j], cs.x, s1);                 \
            s1 = fmaf(hi1[j], cs.y, s1);                 \
        }                                                \
        ow[(size_t)(t + U) * (VV / 2)] =                 \
            make_float2(AV.x + s0, AV.y + s1);           \
    } while (0)

    for (int t = 0; t < ATL; t += 4) {
        float2 a0 = xrd[(size_t)(t + 0) * (VV / 2)];
        float2 a1 = xrd[(size_t)(t + 1) * (VV / 2)];
        float2 a2 = xrd[(size_t)(t + 2) * (VV / 2)];
        float2 a3 = xrd[(size_t)(t + 3) * (VV / 2)];
        APPLY_T(0, a0); APPLY_T(1, a1); APPLY_T(2, a2); APPLY_T(3, a3);
    }
#undef APPLY_T
}

// ---------------- Kernel 3b: fade tiles (both H sets) ----------------
// grid (BB, 2): tiles 7,8 (t in [448,576)).
__global__ __launch_bounds__(256, 2) void k_apply_fade(const float* __restrict__ x,
                                                       const float* __restrict__ H,
                                                       float* __restrict__ out) {
    const int b   = blockIdx.x;
    const int tz  = blockIdx.y;
    const int tid = threadIdx.x;
    const int t0  = (7 + tz) * ATL;

    __shared__ float2 tab[ATL][NB];
    for (int i = tid; i < ATL * NB; i += 256) {
        int t = i >> 4, j = i & 15;
        int idx = (KB[j] * (t0 + t)) & (T_LEN - 1);
        float ss, cc; sincosf(ANG_STEP * (float)idx, &ss, &cc);
        tab[t][j] = make_float2(cc, ss);
    }
    __syncthreads();

    float er0[NB], ei0[NB], er1[NB], ei1[NB];
    float lr0[NB], li0[NB], lr1[NB], li1[NB];
    const float2* hp = (const float2*)(H + (size_t)b * 64 * VV) + tid;
#pragma unroll
    for (int j = 0; j < NB; ++j) {
        float2 a  = hp[(size_t)j        * (VV / 2)]; er0[j] = a.x;  er1[j] = a.y;
        float2 bq = hp[(size_t)(16 + j) * (VV / 2)]; ei0[j] = bq.x; ei1[j] = bq.y;
        float2 cq = hp[(size_t)(32 + j) * (VV / 2)]; lr0[j] = cq.x; lr1[j] = cq.y;
        float2 dq = hp[(size_t)(48 + j) * (VV / 2)]; li0[j] = dq.x; li1[j] = dq.y;
    }

    const float2* xrd = (const float2*)(x + ((size_t)b * T_LEN + t0) * VV) + tid;
    float2*       ow  = (float2*)(out + ((size_t)b * T_LEN + t0) * VV) + tid;

    for (int t = 0; t < ATL; t += 2) {
        float2 a0 = xrd[(size_t)(t + 0) * (VV / 2)];
        float2 a1 = xrd[(size_t)(t + 1) * (VV / 2)];
#pragma unroll
        for (int u = 0; u < 2; ++u) {
            float2 av = u ? a1 : a0;
            const int tg = t0 + t + u;
            float se0 = 0.f, se1 = 0.f, sl0 = 0.f, sl1 = 0.f;
#pragma unroll
            for (int j = 0; j < NB; ++j) {
                float2 cs = tab[t + u][j];
                se0 = fmaf(er0[j], cs.x, se0); se0 = fmaf(ei0[j], cs.y, se0);
                se1 = fmaf(er1[j], cs.x, se1); se1 = fmaf(ei1[j], cs.y, se1);
                sl0 = fmaf(lr0[j], cs.x, sl0); sl0 = fmaf(li0[j], cs.y, sl0);
                sl1 = fmaf(lr1[j], cs.x, sl1); sl1 = fmaf(li1[j], cs.y, sl1);
            }
            float w = (tg < FADE_S) ? 1.0f
                    : ((tg < FADE_E) ? (1.0f - (float)(tg - FADE_S) * (1.0f / 50.0f)) : 0.0f);
            float2 ov;
            ov.x = av.x + fmaf(w, se0 - sl0, sl0);
            ov.y = av.y + fmaf(w, se1 - sl1, sl1);
            ow[(size_t)(t + u) * (VV / 2)] = ov;
        }
    }
}

extern "C" void kernel_launch(void* const* d_in, const int* in_sizes, int n_in,
                              void* d_out, int out_size, void* d_ws, size_t ws_size,
                              hipStream_t stream) {
    (void)in_sizes; (void)n_in; (void)out_size;
    const float* x   = (const float*)d_in[0];
    const float* ger = (const float*)d_in[1];
    const float* gei = (const float*)d_in[2];
    const float* glr = (const float*)d_in[3];
    const float* gli = (const float*)d_in[4];
    float* out = (float*)d_out;

    const size_t hflts = (size_t)BB * 64 * VV;
    int TC;
    if (((size_t)BB * 16 * 32 * VV + hflts) * sizeof(float) <= ws_size)      TC = 16;
    else if (((size_t)BB * 8 * 32 * VV + hflts) * sizeof(float) <= ws_size)  TC = 8;
    else                                                                     TC = 4;

    float* xpart = (float*)d_ws;
    float* H     = xpart + (size_t)BB * TC * 32 * VV;

    if (TC == 16)      k_dft_partial<64> <<<dim3(BB, 16), 256, 0, stream>>>(x, xpart, 16);
    else if (TC == 8)  k_dft_partial<128><<<dim3(BB, 8),  256, 0, stream>>>(x, xpart, 8);
    else               k_dft_partial<256><<<dim3(BB, 4),  256, 0, stream>>>(x, xpart, 4);

    k_combine<<<dim3(BB, NB), 256, 0, stream>>>(xpart, ger, gei, glr, gli, H, TC);
    k_apply_pure<<<dim3(BB, 14), 256, 0, stream>>>(x, H, out);
    k_apply_fade<<<dim3(BB, 2),  256, 0, stream>>>(x, H, out);
}

// Round 4
// 149.174 us; speedup vs baseline: 3.8110x; 3.8110x over previous
//
#include <hip/hip_runtime.h>
#include <math.h>

#define T_LEN 1024
#define VV 512
#define BB 64
#define NB 16
#define ANG_STEP 0.006135923151542565f   // 2*pi/1024
#define FADE_S 487
#define FADE_E 537
#define ATL 64

__device__ constexpr int KB[NB] = {1,2,3,4,5,6,7,8,12,16,24,32,48,64,96,128};

// ---------------- Kernel 1: partial 16-bin DFT over a t-chunk ----------------
// grid (BB, TC), block 512, thread owns v = tid. ~50 VGPRs live -> no spill.
// Partials: xp[((b*TC + tc)*32 + q)*VV + v], q in [0,16)=re_j, [16,32)=im_j
template<int TLEN>
__global__ __launch_bounds__(512) void k_dft_partial(const float* __restrict__ x,
                                                     float* __restrict__ xpart,
                                                     int tc_count) {
    const int b   = blockIdx.x;
    const int tc  = blockIdx.y;
    const int tid = threadIdx.x;
    const int t0  = tc * TLEN;

    __shared__ float2 tab[TLEN][NB];
    for (int i = tid; i < TLEN * NB; i += 512) {
        int t = i >> 4, j = i & 15;
        int idx = (KB[j] * (t0 + t)) & (T_LEN - 1);
        float ss, cc; sincosf(ANG_STEP * (float)idx, &ss, &cc);
        tab[t][j] = make_float2(cc, ss);
    }
    __syncthreads();

    float xr[NB], xi[NB];
#pragma unroll
    for (int j = 0; j < NB; ++j) { xr[j] = 0.f; xi[j] = 0.f; }

    const float* xrd = x + ((size_t)b * T_LEN + t0) * VV + tid;

#define DFT_T(U, AV)                                    \
    do {                                                \
        _Pragma("unroll")                               \
        for (int j = 0; j < NB; ++j) {                  \
            float2 cs = tab[t + U][j];                  \
            xr[j] = fmaf(AV, cs.x, xr[j]);              \
            xi[j] = fmaf(-AV, cs.y, xi[j]);             \
        }                                               \
    } while (0)

    for (int t = 0; t < TLEN; t += 4) {
        float a0 = xrd[(size_t)(t + 0) * VV];
        float a1 = xrd[(size_t)(t + 1) * VV];
        float a2 = xrd[(size_t)(t + 2) * VV];
        float a3 = xrd[(size_t)(t + 3) * VV];
        DFT_T(0, a0); DFT_T(1, a1); DFT_T(2, a2); DFT_T(3, a3);
    }
#undef DFT_T

    float* o = xpart + (size_t)(b * tc_count + tc) * 32 * VV + tid;
#pragma unroll
    for (int j = 0; j < NB; ++j) {
        o[(size_t)j        * VV] = xr[j];
        o[(size_t)(NB + j) * VV] = xi[j];
    }
}

// ---------------- Kernel 2: reduce partials, apply gains -> H ----------------
// grid (BB, NB): one j-bin per block (1024 blocks). Tiny per-thread state.
// H layout: H[b][q][v], q: [0,16)=He_re, [16,32)=-He_im, [32,48)=Hl_re, [48,64)=-Hl_im
__global__ __launch_bounds__(256) void k_combine(const float* __restrict__ xpart,
                                                 const float* __restrict__ ger,
                                                 const float* __restrict__ gei,
                                                 const float* __restrict__ glr,
                                                 const float* __restrict__ gli,
                                                 float* __restrict__ H, int tc_count) {
    const int b   = blockIdx.x;
    const int j   = blockIdx.y;
    const int tid = threadIdx.x;
    const int v0  = tid * 2;

    float re0 = 0.f, re1 = 0.f, im0 = 0.f, im1 = 0.f;
#pragma unroll 8
    for (int tc = 0; tc < tc_count; ++tc) {
        const float2* p = (const float2*)(xpart + (size_t)(b * tc_count + tc) * 32 * VV) + tid;
        float2 a  = p[(size_t)j        * (VV / 2)];
        float2 bb = p[(size_t)(NB + j) * (VV / 2)];
        re0 += a.x;  re1 += a.y;
        im0 += bb.x; im1 += bb.y;
    }

    const float scale = 2.0f / (float)T_LEN;
    float er0 = ger[v0 * NB + j],       ei0 = gei[v0 * NB + j];
    float lr0 = glr[v0 * NB + j],       li0 = gli[v0 * NB + j];
    float er1 = ger[(v0 + 1) * NB + j], ei1 = gei[(v0 + 1) * NB + j];
    float lr1 = glr[(v0 + 1) * NB + j], li1 = gli[(v0 + 1) * NB + j];

    float here0 = (re0 * er0 - im0 * ei0) * scale;
    float heim0 = (re0 * ei0 + im0 * er0) * scale;
    float hlre0 = (re0 * lr0 - im0 * li0) * scale;
    float hlim0 = (re0 * li0 + im0 * lr0) * scale;
    float here1 = (re1 * er1 - im1 * ei1) * scale;
    float heim1 = (re1 * ei1 + im1 * er1) * scale;
    float hlre1 = (re1 * lr1 - im1 * li1) * scale;
    float hlim1 = (re1 * li1 + im1 * lr1) * scale;

    float2* o = (float2*)(H + (size_t)b * 64 * VV) + tid;
    o[(size_t)j        * (VV / 2)] = make_float2(here0, here1);
    o[(size_t)(16 + j) * (VV / 2)] = make_float2(-heim0, -heim1);
    o[(size_t)(32 + j) * (VV / 2)] = make_float2(hlre0, hlre1);
    o[(size_t)(48 + j) * (VV / 2)] = make_float2(-hlim0, -hlim1);
}

// ---------------- Kernel 3a: pure-early/late tiles (single H set) ----------------
// grid (BB, 14), block 512, thread owns v = tid. 32 H regs -> ~48 VGPR, no spill.
__global__ __launch_bounds__(512) void k_apply_pure(const float* __restrict__ x,
                                                    const float* __restrict__ H,
                                                    float* __restrict__ out) {
    const int b    = blockIdx.x;
    const int ti   = blockIdx.y;
    const int tid  = threadIdx.x;
    const int tile = (ti < 7) ? ti : ti + 2;
    const int t0   = tile * ATL;
    const int qo   = (ti < 7) ? 0 : 32;

    __shared__ float2 tab[ATL][NB];
    for (int i = tid; i < ATL * NB; i += 512) {
        int t = i >> 4, j = i & 15;
        int idx = (KB[j] * (t0 + t)) & (T_LEN - 1);
        float ss, cc; sincosf(ANG_STEP * (float)idx, &ss, &cc);
        tab[t][j] = make_float2(cc, ss);
    }

    float hr[NB], hi[NB];
    const float* hp = H + (size_t)b * 64 * VV + tid;
#pragma unroll
    for (int j = 0; j < NB; ++j) {
        hr[j] = hp[(size_t)(qo + j)      * VV];
        hi[j] = hp[(size_t)(qo + 16 + j) * VV];
    }
    __syncthreads();

    const float* xrd = x + ((size_t)b * T_LEN + t0) * VV + tid;
    float*       ow  = out + ((size_t)b * T_LEN + t0) * VV + tid;

#define APPLY_T(U, AV)                                   \
    do {                                                 \
        float s = 0.f;                                   \
        _Pragma("unroll")                                \
        for (int j = 0; j < NB; ++j) {                   \
            float2 cs = tab[t + U][j];                   \
            s = fmaf(hr[j], cs.x, s);                    \
            s = fmaf(hi[j], cs.y, s);                    \
        }                                                \
        ow[(size_t)(t + U) * VV] = AV + s;               \
    } while (0)

    for (int t = 0; t < ATL; t += 4) {
        float a0 = xrd[(size_t)(t + 0) * VV];
        float a1 = xrd[(size_t)(t + 1) * VV];
        float a2 = xrd[(size_t)(t + 2) * VV];
        float a3 = xrd[(size_t)(t + 3) * VV];
        APPLY_T(0, a0); APPLY_T(1, a1); APPLY_T(2, a2); APPLY_T(3, a3);
    }
#undef APPLY_T
}

// ---------------- Kernel 3b: fade tiles (both H sets) ----------------
// grid (BB, 2), block 512, thread owns v = tid. 64 H regs + temps ~80.
__global__ __launch_bounds__(512) void k_apply_fade(const float* __restrict__ x,
                                                    const float* __restrict__ H,
                                                    float* __restrict__ out) {
    const int b   = blockIdx.x;
    const int tz  = blockIdx.y;
    const int tid = threadIdx.x;
    const int t0  = (7 + tz) * ATL;

    __shared__ float2 tab[ATL][NB];
    for (int i = tid; i < ATL * NB; i += 512) {
        int t = i >> 4, j = i & 15;
        int idx = (KB[j] * (t0 + t)) & (T_LEN - 1);
        float ss, cc; sincosf(ANG_STEP * (float)idx, &ss, &cc);
        tab[t][j] = make_float2(cc, ss);
    }

    float er[NB], ei[NB], lr[NB], li[NB];
    const float* hp = H + (size_t)b * 64 * VV + tid;
#pragma unroll
    for (int j = 0; j < NB; ++j) {
        er[j] = hp[(size_t)j        * VV];
        ei[j] = hp[(size_t)(16 + j) * VV];
        lr[j] = hp[(size_t)(32 + j) * VV];
        li[j] = hp[(size_t)(48 + j) * VV];
    }
    __syncthreads();

    const float* xrd = x + ((size_t)b * T_LEN + t0) * VV + tid;
    float*       ow  = out + ((size_t)b * T_LEN + t0) * VV + tid;

    for (int t = 0; t < ATL; t += 2) {
        float a0 = xrd[(size_t)(t + 0) * VV];
        float a1 = xrd[(size_t)(t + 1) * VV];
#pragma unroll
        for (int u = 0; u < 2; ++u) {
            float av = u ? a1 : a0;
            const int tg = t0 + t + u;
            float se = 0.f, sl = 0.f;
#pragma unroll
            for (int j = 0; j < NB; ++j) {
                float2 cs = tab[t + u][j];
                se = fmaf(er[j], cs.x, se); se = fmaf(ei[j], cs.y, se);
                sl = fmaf(lr[j], cs.x, sl); sl = fmaf(li[j], cs.y, sl);
            }
            float w = (tg < FADE_S) ? 1.0f
                    : ((tg < FADE_E) ? (1.0f - (float)(tg - FADE_S) * (1.0f / 50.0f)) : 0.0f);
            ow[(size_t)(t + u) * VV] = av + fmaf(w, se - sl, sl);
        }
    }
}

extern "C" void kernel_launch(void* const* d_in, const int* in_sizes, int n_in,
                              void* d_out, int out_size, void* d_ws, size_t ws_size,
                              hipStream_t stream) {
    (void)in_sizes; (void)n_in; (void)out_size;
    const float* x   = (const float*)d_in[0];
    const float* ger = (const float*)d_in[1];
    const float* gei = (const float*)d_in[2];
    const float* glr = (const float*)d_in[3];
    const float* gli = (const float*)d_in[4];
    float* out = (float*)d_out;

    const size_t hflts = (size_t)BB * 64 * VV;
    int TC;
    if (((size_t)BB * 8 * 32 * VV + hflts) * sizeof(float) <= ws_size)  TC = 8;
    else                                                                TC = 4;

    float* xpart = (float*)d_ws;
    float* H     = xpart + (size_t)BB * TC * 32 * VV;

    if (TC == 8) k_dft_partial<128><<<dim3(BB, 8), 512, 0, stream>>>(x, xpart, 8);
    else         k_dft_partial<256><<<dim3(BB, 4), 512, 0, stream>>>(x, xpart, 4);

    k_combine<<<dim3(BB, NB), 256, 0, stream>>>(xpart, ger, gei, glr, gli, H, TC);
    k_apply_pure<<<dim3(BB, 14), 512, 0, stream>>>(x, H, out);
    k_apply_fade<<<dim3(BB, 2),  512, 0, stream>>>(x, H, out);
}